// Round 1
// baseline (28.633 us; speedup 1.0000x reference)
//
#include <hip/hip_runtime.h>

#define BATCH 16
#define LEN 512
#define HID 384
#define TOUT 3584           // LEN * (DUR_MAX-1) = 512*7
#define VEC (HID / 4)       // 96 float4 per row

// Kernel 1: inclusive cumsum of durations per batch row.
__global__ void cumsum_kernel(const int* __restrict__ dur, int* __restrict__ cs) {
    __shared__ int s[LEN];
    const int b = blockIdx.x;
    const int tid = threadIdx.x;           // 512 threads
    s[tid] = dur[b * LEN + tid];
    __syncthreads();
    for (int off = 1; off < LEN; off <<= 1) {
        int v = (tid >= off) ? s[tid - off] : 0;
        __syncthreads();
        s[tid] += v;
        __syncthreads();
    }
    cs[b * LEN + tid] = s[tid];
}

// Kernel 2: per (b,t) searchsorted(cs, t, side='right'), clipped; emit
// gather index (-1 when masked out) and the mask as float 1/0.
__global__ void idx_kernel(const int* __restrict__ cs,
                           int* __restrict__ idxm,
                           float* __restrict__ mask_out) {
    __shared__ int s[LEN];
    const int b = blockIdx.y;
    const int tid = threadIdx.x;           // 256 threads
    s[tid]       = cs[b * LEN + tid];
    s[tid + 256] = cs[b * LEN + tid + 256];
    __syncthreads();
    const int t = blockIdx.x * 256 + tid;
    if (t < TOUT) {
        const int total = s[LEN - 1];
        int lo = 0, hi = LEN;
        while (lo < hi) {
            int mid = (lo + hi) >> 1;
            if (s[mid] <= t) lo = mid + 1; else hi = mid;
        }
        int idx = lo < (LEN - 1) ? lo : (LEN - 1);
        const bool m = t < total;
        idxm[b * TOUT + t]     = m ? idx : -1;
        mask_out[b * TOUT + t] = m ? 1.0f : 0.0f;
    }
}

// Kernel 3: vectorized gather-copy. One float4 per thread.
__global__ void gather_kernel(const float4* __restrict__ ehs,
                              const int* __restrict__ idxm,
                              float4* __restrict__ out) {
    const long long i = (long long)blockIdx.x * blockDim.x + threadIdx.x;
    const long long n = (long long)BATCH * TOUT * VEC;
    if (i >= n) return;
    const int row = (int)(i / VEC);        // b*TOUT + t
    const int col = (int)(i - (long long)row * VEC);
    const int iv = idxm[row];
    float4 r = make_float4(0.f, 0.f, 0.f, 0.f);
    if (iv >= 0) {
        const int b = row / TOUT;
        r = ehs[((long long)b * LEN + iv) * VEC + col];
    }
    out[i] = r;
}

extern "C" void kernel_launch(void* const* d_in, const int* in_sizes, int n_in,
                              void* d_out, int out_size, void* d_ws, size_t ws_size,
                              hipStream_t stream) {
    const float* ehs = (const float*)d_in[0];
    const int* dur   = (const int*)d_in[1];
    // d_in[2] = max_durations scalar; compile-time constant TOUT used instead.

    float* out_expanded = (float*)d_out;                                  // [B,T,H]
    float* out_mask     = (float*)d_out + (long long)BATCH * TOUT * HID;  // [B,T]

    int* cs   = (int*)d_ws;                       // BATCH*LEN ints (32 KB)
    int* idxm = (int*)d_ws + BATCH * LEN;         // BATCH*TOUT ints (224 KB)

    cumsum_kernel<<<BATCH, LEN, 0, stream>>>(dur, cs);

    dim3 g2(TOUT / 256, BATCH);
    idx_kernel<<<g2, 256, 0, stream>>>(cs, idxm, out_mask);

    const long long nvec = (long long)BATCH * TOUT * VEC;   // 5,505,024
    const int blocks = (int)((nvec + 255) / 256);
    gather_kernel<<<blocks, 256, 0, stream>>>((const float4*)ehs, idxm, (float4*)out_expanded);
}

// Round 2
// 21.561 us; speedup vs baseline: 1.3280x; 1.3280x over previous
//
#include <hip/hip_runtime.h>

#define BATCH 16
#define LEN 512
#define HID 384
#define TOUT 3584            // LEN * (DUR_MAX-1) = 512*7
#define VEC (HID / 4)        // 96 float4 per output row
#define TPB 512              // threads per block (= LEN, for the scan)
#define T_TILE 64            // output timesteps per block; TOUT/T_TILE = 56

// One fused kernel: per-block (b, 64-timestep tile):
//   phase 1: load duration row, inclusive scan in LDS (9 steps)
//   phase 2: binary search for the tile's 64 timesteps -> gather idx / mask
//   phase 3: stream 64*96 float4 gathered writes (12 per thread)
__global__ void __launch_bounds__(TPB)
fused_length_regulator(const float4* __restrict__ ehs,
                       const int* __restrict__ dur,
                       float4* __restrict__ out,
                       float* __restrict__ mask_out) {
    __shared__ int s[LEN];
    __shared__ int sidx[T_TILE];

    const int b   = blockIdx.y;
    const int tid = threadIdx.x;

    // phase 1: inclusive cumsum of durations[b, :]
    s[tid] = dur[b * LEN + tid];
    __syncthreads();
    for (int off = 1; off < LEN; off <<= 1) {
        int v = (tid >= off) ? s[tid - off] : 0;
        __syncthreads();
        s[tid] += v;
        __syncthreads();
    }

    // phase 2: searchsorted(cs, t, side='right') for this block's 64 t's
    const int t0 = blockIdx.x * T_TILE;
    if (tid < T_TILE) {
        const int t = t0 + tid;
        const int total = s[LEN - 1];
        int lo = 0, hi = LEN;
        while (lo < hi) {
            int mid = (lo + hi) >> 1;
            if (s[mid] <= t) lo = mid + 1; else hi = mid;
        }
        int idx = lo < (LEN - 1) ? lo : (LEN - 1);
        const bool m = t < total;
        sidx[tid] = m ? idx : -1;
        mask_out[b * TOUT + t] = m ? 1.0f : 0.0f;
    }
    __syncthreads();

    // phase 3: gathered streaming copy, 64 rows x 96 float4 = 6144 float4
    const float4* __restrict__ src_b = ehs + (long long)b * LEN * VEC;
    float4* __restrict__ dst = out + ((long long)b * TOUT + t0) * VEC;
    #pragma unroll
    for (int it = 0; it < (T_TILE * VEC) / TPB; ++it) {   // 12 iterations
        const int j = it * TPB + tid;
        const int r = j / VEC;            // 0..63 (magic-mul by compiler)
        const int c = j - r * VEC;
        const int iv = sidx[r];
        float4 v = make_float4(0.f, 0.f, 0.f, 0.f);
        if (iv >= 0) v = src_b[iv * VEC + c];
        dst[j] = v;
    }
}

extern "C" void kernel_launch(void* const* d_in, const int* in_sizes, int n_in,
                              void* d_out, int out_size, void* d_ws, size_t ws_size,
                              hipStream_t stream) {
    const float* ehs = (const float*)d_in[0];
    const int* dur   = (const int*)d_in[1];
    // d_in[2] = max_durations scalar; compile-time constant TOUT used.

    float* out_expanded = (float*)d_out;                                  // [B,T,H]
    float* out_mask     = (float*)d_out + (long long)BATCH * TOUT * HID;  // [B,T]

    dim3 grid(TOUT / T_TILE, BATCH);   // 56 x 16 = 896 blocks
    fused_length_regulator<<<grid, TPB, 0, stream>>>(
        (const float4*)ehs, dur, (float4*)out_expanded, out_mask);
}